// Round 2
// baseline (690.739 us; speedup 1.0000x reference)
//
#include <hip/hip_runtime.h>
#include <hip/hip_bf16.h>

// HopfieldLayer: out = softmax(x @ Wl^T * beta) @ Wc^T
//   x [16384,768] f32, Wl [4096,768] f32, Wc [768,4096] f32 -> out [16384,768] f32
// R5: de-serialized pipeline. One barrier per phase; ds_reads for phase p+1
// issued during phase p into double-buffered frag regs (compiler inserts
// counted lgkm waits); counted vmcnt(4) once per K-tile; sched_barrier(0)
// pins phase boundaries. LDS fragment-ordered (conflict-free, measured 0).

#define NTOK   16384
#define DIM    768
#define NPROT  4096
#define BETA_F 0.03608439182428583f

typedef __bf16 bf16_t;
typedef __bf16 bf16x8 __attribute__((ext_vector_type(8)));
typedef float  floatx4 __attribute__((ext_vector_type(4)));

// ---------------------------------------------------------------- async 16B copy
__device__ __forceinline__ void async_copy16(const bf16_t* g, void* l) {
  __builtin_amdgcn_global_load_lds(
      (__attribute__((address_space(1))) const void*)g,
      (__attribute__((address_space(3))) void*)l, 16, 0, 0);
}

// ---------------------------------------------------------------- f32 -> bf16
__global__ __launch_bounds__(256) void cvt_all(
    const float* __restrict__ x, const float* __restrict__ wl,
    const float* __restrict__ wc, bf16_t* __restrict__ xb,
    bf16_t* __restrict__ wlb, bf16_t* __restrict__ wcb,
    int nx8, int nw8, int nc8) {
  int i = blockIdx.x * 256 + threadIdx.x;
  const float* in; bf16_t* out; int k;
  if (i < nx8)            { in = x;  out = xb;  k = i; }
  else if (i < nx8 + nw8) { in = wl; out = wlb; k = i - nx8; }
  else if (i < nx8 + nw8 + nc8) { in = wc; out = wcb; k = i - nx8 - nw8; }
  else return;
  const float4* in4 = (const float4*)in;
  float4 a = in4[2 * k], b = in4[2 * k + 1];
  bf16x8 o;
  o[0] = (bf16_t)a.x; o[1] = (bf16_t)a.y; o[2] = (bf16_t)a.z; o[3] = (bf16_t)a.w;
  o[4] = (bf16_t)b.x; o[5] = (bf16_t)b.y; o[6] = (bf16_t)b.z; o[7] = (bf16_t)b.w;
  ((bf16x8*)out)[k] = o;
}

// ---------------------------------------------------------------- gemm C = A * B^T
// 256x256 tile, BK=64, 8 waves 2(M)x4(N). Wave frag rows mfrag = mt*2+wr
// (mt 0..7), cols nfrag = nt*4+wc (nt 0..3). LDS: 32 subfrags of 1KB per
// operand; subfrag (frag,ks): entry l -> row frag*16+(l&15), k ks*32+(l>>4)*8.
// Slots: tile parity. Per K-tile: 4 phases (af quadrants mq0..3), each:
//   { stage 1 half-tile ; issue next phase's ds_reads ; 16 MFMA ; [VM(4)@c2] ; BAR }
// Stage ledger (one-barrier separation, verified):
//   x.c0: A(x+1)h1   x.c1: B(x+2)h0   x.c2: B(x+2)h1 +VM(4)   x.c3: A(x+2)h0
template <int EPI>
__global__ __launch_bounds__(512, 2)
void gemm256(const bf16_t* __restrict__ A, const bf16_t* __restrict__ B,
             void* __restrict__ Cv, float* __restrict__ rowsum,
             const int K, const int N, const int nN) {
  __shared__ char lds[131072];

  const int tid = threadIdx.x;
  const int l   = tid & 63;
  const int w   = tid >> 6;       // 0..7
  const int wr  = w >> 2;         // 0..1  (M)
  const int wc  = w & 3;          // 0..3  (N)
  const int lr  = l & 15;
  const int lk  = (l >> 4) << 3;  // 0,8,16,24

  // bijective XCD swizzle (nwg % 8 == 0); n-fast within chunk
  const int nwg   = gridDim.x;
  const int chunk = nwg >> 3;
  const int wg    = (blockIdx.x & 7) * chunk + (blockIdx.x >> 3);
  const int m0    = (wg / nN) * 256;
  const int n0    = (wg % nN) * 256;

  // staging: thread (w,l), j in {0,1} -> subfrag s=j*8+w of a half-tile
  int aoff[2][2], boff[2][2];
#pragma unroll
  for (int h = 0; h < 2; ++h)
#pragma unroll
    for (int j = 0; j < 2; ++j) {
      const int s     = j * 8 + w;
      const int mfrag = h * 8 + (s >> 1);
      const int ks    = s & 1;
      aoff[h][j] = (m0 + mfrag * 16 + lr) * K + ks * 32 + lk;
      boff[h][j] = (n0 + mfrag * 16 + lr) * K + ks * 32 + lk;
    }

  auto stageA = [&](int slot, int kt, int h) {
#pragma unroll
    for (int j = 0; j < 2; ++j) {
      const int s  = j * 8 + w;
      const int sf = (h * 8 + (s >> 1)) * 2 + (s & 1);
      async_copy16(A + aoff[h][j] + kt * 64, lds + slot * 65536 + sf * 1024);
    }
  };
  auto stageB = [&](int slot, int kt, int h) {
#pragma unroll
    for (int j = 0; j < 2; ++j) {
      const int s  = j * 8 + w;
      const int sf = (h * 8 + (s >> 1)) * 2 + (s & 1);
      async_copy16(B + boff[h][j] + kt * 64,
                   lds + slot * 65536 + 32768 + sf * 1024);
    }
  };

  // fragment register sets (double-buffered)
  bf16x8 afA[2][2], afB[2][2];   // 16 VGPR each
  bf16x8 bgA[4][2], bgB[4][2];   // 32 VGPR each

  auto loadAf = [&](bf16x8 (&dst)[2][2], int slot, int mq) {
#pragma unroll
    for (int q = 0; q < 2; ++q)
#pragma unroll
      for (int ks = 0; ks < 2; ++ks)
        dst[q][ks] = *(const bf16x8*)(lds + slot * 65536 +
                        ((4 * mq + 2 * q + wr) * 2 + ks) * 1024 + l * 16);
  };
  auto loadBg = [&](bf16x8 (&dst)[4][2], int slot) {
#pragma unroll
    for (int nt = 0; nt < 4; ++nt)
#pragma unroll
      for (int ks = 0; ks < 2; ++ks)
        dst[nt][ks] = *(const bf16x8*)(lds + slot * 65536 + 32768 +
                        ((nt * 4 + wc) * 2 + ks) * 1024 + l * 16);
  };

  const floatx4 z = {0.f, 0.f, 0.f, 0.f};
  floatx4 acc[8][4];
#pragma unroll
  for (int mt = 0; mt < 8; ++mt)
#pragma unroll
    for (int nt = 0; nt < 4; ++nt) acc[mt][nt] = z;

  auto mma = [&](const bf16x8 (&af)[2][2], const bf16x8 (&bg)[4][2], int mq) {
    __builtin_amdgcn_s_setprio(1);
#pragma unroll
    for (int q = 0; q < 2; ++q)
#pragma unroll
      for (int nt = 0; nt < 4; ++nt)
#pragma unroll
        for (int ks = 0; ks < 2; ++ks)
          acc[2 * mq + q][nt] = __builtin_amdgcn_mfma_f32_16x16x32_bf16(
              af[q][ks], bg[nt][ks], acc[2 * mq + q][nt], 0, 0, 0);
    __builtin_amdgcn_s_setprio(0);
  };

#define BAR()    do { __builtin_amdgcn_s_barrier(); \
                      __builtin_amdgcn_sched_barrier(0); } while (0)
#define VM(n)    asm volatile("s_waitcnt vmcnt(" #n ")" ::: "memory")

  const int T = K >> 6;  // 12 (K=768) or 64 (K=4096); even, >= 4

  // prologue: tile0 full + tile1 {B-h0, B-h1, A-h0}; tile1 A-h1 at 0.c0
  stageA(0, 0, 0); stageA(0, 0, 1); stageB(0, 0, 0); stageB(0, 0, 1);
  stageB(1, 1, 0); stageB(1, 1, 1); stageA(1, 1, 0);
  VM(6);  // tile0's 8 loads landed; tile1's 6 stay in flight
  BAR();
  loadAf(afA, 0, 0);
  loadBg(bgA, 0);

#pragma unroll 1
  for (int x = 0; x + 3 < T; x += 2) {    // pairs; even tile -> slot0/bgA
    // ---- tile x (even, slot0) ----
    stageA(1, x + 1, 1);                  // A(x+1) h1
    loadAf(afB, 0, 1);
    mma(afA, bgA, 0); BAR();
    stageB(0, x + 2, 0);                  // B(x+2) h0
    loadAf(afA, 0, 2);
    mma(afB, bgA, 1); BAR();
    stageB(0, x + 2, 1);                  // B(x+2) h1
    loadAf(afB, 0, 3);
    mma(afA, bgA, 2);
    VM(4);                                // tile x+1 fully landed
    BAR();
    stageA(0, x + 2, 0);                  // A(x+2) h0
    loadAf(afA, 1, 0);
    loadBg(bgB, 1);
    mma(afB, bgA, 3); BAR();
    // ---- tile x+1 (odd, slot1) ----
    stageA(0, x + 2, 1);                  // A(x+2) h1
    loadAf(afB, 1, 1);
    mma(afA, bgB, 0); BAR();
    stageB(1, x + 3, 0);                  // B(x+3) h0
    loadAf(afA, 1, 2);
    mma(afB, bgB, 1); BAR();
    stageB(1, x + 3, 1);                  // B(x+3) h1
    loadAf(afB, 1, 3);
    mma(afA, bgB, 2);
    VM(4);                                // tile x+2 fully landed
    BAR();
    stageA(1, x + 3, 0);                  // A(x+3) h0
    loadAf(afA, 0, 0);                    // af(x+2, mq0)
    loadBg(bgA, 0);                       // bg(x+2)
    mma(afB, bgB, 3); BAR();
  }

  // ---- tail: tiles T-2 (slot0, bgA) and T-1 (slot1) ----
  stageA(1, T - 1, 1);                    // A(T-1) h1 (last stage)
  loadAf(afB, 0, 1);
  mma(afA, bgA, 0); BAR();
  loadAf(afA, 0, 2);
  mma(afB, bgA, 1); BAR();
  loadAf(afB, 0, 3);
  mma(afA, bgA, 2);
  VM(0);                                  // tile T-1 fully landed
  BAR();
  loadAf(afA, 1, 0);
  loadBg(bgB, 1);
  mma(afB, bgA, 3); BAR();
  loadAf(afB, 1, 1);
  mma(afA, bgB, 0); BAR();
  loadAf(afA, 1, 2);
  mma(afB, bgB, 1); BAR();
  loadAf(afB, 1, 3);
  mma(afA, bgB, 2); BAR();
  mma(afB, bgB, 3);

#undef BAR
#undef VM

  // C/D layout: col = lane&15, row = (lane>>4)*4 + i
  // frag (mt,nt): row = m0+(mt*2+wr)*16+(l>>4)*4+i, col = n0+(nt*4+wc)*16+lr
  const int hi4 = (l >> 4) << 2;
  if (EPI == 0) {
    bf16_t* P = (bf16_t*)Cv;
#pragma unroll
    for (int mt = 0; mt < 8; ++mt) {
      const int row = m0 + (mt * 2 + wr) * 16 + hi4;
      float rs[4] = {0.f, 0.f, 0.f, 0.f};
#pragma unroll
      for (int nt = 0; nt < 4; ++nt) {
        const int col = n0 + (nt * 4 + wc) * 16 + lr;
#pragma unroll
        for (int i = 0; i < 4; ++i) {
          const float e = __expf(acc[mt][nt][i] * BETA_F);
          P[(row + i) * N + col] = (bf16_t)e;
          rs[i] += e;
        }
      }
#pragma unroll
      for (int i = 0; i < 4; ++i) {  // reduce over the 16 col-lanes
        float s = rs[i];
        s += __shfl_xor(s, 1);
        s += __shfl_xor(s, 2);
        s += __shfl_xor(s, 4);
        s += __shfl_xor(s, 8);
        if (lr == 0) atomicAdd(&rowsum[row + i], s);
      }
    }
  } else {
    float* O = (float*)Cv;
#pragma unroll
    for (int mt = 0; mt < 8; ++mt) {
      const int row = m0 + (mt * 2 + wr) * 16 + hi4;
#pragma unroll
      for (int i = 0; i < 4; ++i) {
        const float inv = 1.0f / rowsum[row + i];
#pragma unroll
        for (int nt = 0; nt < 4; ++nt)
          O[(row + i) * N + n0 + (nt * 4 + wc) * 16 + lr] = acc[mt][nt][i] * inv;
      }
    }
  }
}

// ---------------------------------------------------------------- fallback (no ws)
__global__ __launch_bounds__(256) void hopfield_fallback(
    const float* __restrict__ x, const float* __restrict__ wl,
    const float* __restrict__ wc, float* __restrict__ out) {
  __shared__ float  xs[8 * 768];
  __shared__ bf16_t ps[8 * 4096];
  __shared__ float  rs[8];
  const int tid = threadIdx.x;
  const int r0  = blockIdx.x * 8;
  if (tid < 8) rs[tid] = 0.f;
  for (int i = tid; i < 8 * 768; i += 256)
    xs[i] = x[(r0 + (i / 768)) * 768 + (i % 768)];
  __syncthreads();

  float lsum[8] = {0, 0, 0, 0, 0, 0, 0, 0};
  for (int p = tid; p < 4096; p += 256) {
    float s[8] = {0, 0, 0, 0, 0, 0, 0, 0};
    for (int d = 0; d < 768; ++d) {
      const float wv = wl[p * 768 + d];
#pragma unroll
      for (int r = 0; r < 8; ++r) s[r] += xs[r * 768 + d] * wv;
    }
#pragma unroll
    for (int r = 0; r < 8; ++r) {
      const float e = __expf(s[r] * BETA_F);
      ps[r * 4096 + p] = (bf16_t)e;
      lsum[r] += e;
    }
  }
#pragma unroll
  for (int r = 0; r < 8; ++r) atomicAdd(&rs[r], lsum[r]);
  __syncthreads();

  for (int d = tid; d < 768; d += 256) {
    float o[8] = {0, 0, 0, 0, 0, 0, 0, 0};
    for (int p = 0; p < 4096; ++p) {
      const float wv = wc[d * 4096 + p];
#pragma unroll
      for (int r = 0; r < 8; ++r) o[r] += (float)ps[r * 4096 + p] * wv;
    }
#pragma unroll
    for (int r = 0; r < 8; ++r) out[(r0 + r) * 768 + d] = o[r] / rs[r];
  }
}

// ---------------------------------------------------------------- launcher
extern "C" void kernel_launch(void* const* d_in, const int* in_sizes, int n_in,
                              void* d_out, int out_size, void* d_ws, size_t ws_size,
                              hipStream_t stream) {
  (void)in_sizes; (void)n_in; (void)out_size;
  const float* x  = (const float*)d_in[0];
  const float* wl = (const float*)d_in[1];
  const float* wc = (const float*)d_in[2];
  float* out = (float*)d_out;

  const size_t xb_e = (size_t)NTOK * DIM;
  const size_t wl_e = (size_t)NPROT * DIM;
  const size_t wc_e = (size_t)DIM * NPROT;
  const size_t P_e  = (size_t)NTOK * NPROT;
  const size_t need = (xb_e + wl_e + wc_e + P_e) * 2 + (size_t)NTOK * 4;

  if (ws_size >= need) {
    char* ws = (char*)d_ws;
    bf16_t* xb  = (bf16_t*)ws;  ws += xb_e * 2;
    bf16_t* wlb = (bf16_t*)ws;  ws += wl_e * 2;
    bf16_t* wcb = (bf16_t*)ws;  ws += wc_e * 2;
    bf16_t* P   = (bf16_t*)ws;  ws += P_e * 2;
    float* rowsum = (float*)ws;

    hipMemsetAsync(rowsum, 0, NTOK * sizeof(float), stream);
    const int nx8 = (int)(xb_e / 8), nw8 = (int)(wl_e / 8), nc8 = (int)(wc_e / 8);
    cvt_all<<<(nx8 + nw8 + nc8 + 255) / 256, 256, 0, stream>>>(
        x, wl, wc, xb, wlb, wcb, nx8, nw8, nc8);
    // scores+exp+rowsum: M=16384, N=4096, K=768 -> 64x16 = 1024 blocks
    gemm256<0><<<dim3((NTOK / 256) * (NPROT / 256)), 512, 0, stream>>>(
        xb, wlb, (void*)P, rowsum, DIM, NPROT, NPROT / 256);
    // content+normalize: M=16384, N=768, K=4096 -> 64x3 = 192 blocks
    gemm256<1><<<dim3((NTOK / 256) * (DIM / 256)), 512, 0, stream>>>(
        P, wcb, (void*)out, rowsum, NPROT, DIM, DIM / 256);
  } else {
    hopfield_fallback<<<NTOK / 8, 256, 0, stream>>>(x, wl, wc, out);
  }
}

// Round 3
// 435.846 us; speedup vs baseline: 1.5848x; 1.5848x over previous
//
#include <hip/hip_runtime.h>
#include <hip/hip_bf16.h>

// HopfieldLayer: out = softmax(x @ Wl^T * beta) @ Wc^T
//   x [16384,768] f32, Wl [4096,768] f32, Wc [768,4096] f32 -> out [16384,768] f32
// R6: R5's one-barrier-per-phase pipeline, spill-fixed. Budget: 8 waves/block,
// LDS-capped 1 block/CU -> 256 regs/wave; acc=128 AGPR leaves 128 arch VGPRs.
// Frags must fit ~64: af double-buffered (32, the de-serializing prefetch),
// bg single-buffered (32, reloaded once per K-tile at c3 after last use).
// Counted vmcnt(4) once per tile; sched_barrier(0) pins phase boundaries.

#define NTOK   16384
#define DIM    768
#define NPROT  4096
#define BETA_F 0.03608439182428583f

typedef __bf16 bf16_t;
typedef __bf16 bf16x8 __attribute__((ext_vector_type(8)));
typedef float  floatx4 __attribute__((ext_vector_type(4)));

// ---------------------------------------------------------------- async 16B copy
__device__ __forceinline__ void async_copy16(const bf16_t* g, void* l) {
  __builtin_amdgcn_global_load_lds(
      (__attribute__((address_space(1))) const void*)g,
      (__attribute__((address_space(3))) void*)l, 16, 0, 0);
}

// ---------------------------------------------------------------- f32 -> bf16
__global__ __launch_bounds__(256) void cvt_all(
    const float* __restrict__ x, const float* __restrict__ wl,
    const float* __restrict__ wc, bf16_t* __restrict__ xb,
    bf16_t* __restrict__ wlb, bf16_t* __restrict__ wcb,
    int nx8, int nw8, int nc8) {
  int i = blockIdx.x * 256 + threadIdx.x;
  const float* in; bf16_t* out; int k;
  if (i < nx8)            { in = x;  out = xb;  k = i; }
  else if (i < nx8 + nw8) { in = wl; out = wlb; k = i - nx8; }
  else if (i < nx8 + nw8 + nc8) { in = wc; out = wcb; k = i - nx8 - nw8; }
  else return;
  const float4* in4 = (const float4*)in;
  float4 a = in4[2 * k], b = in4[2 * k + 1];
  bf16x8 o;
  o[0] = (bf16_t)a.x; o[1] = (bf16_t)a.y; o[2] = (bf16_t)a.z; o[3] = (bf16_t)a.w;
  o[4] = (bf16_t)b.x; o[5] = (bf16_t)b.y; o[6] = (bf16_t)b.z; o[7] = (bf16_t)b.w;
  ((bf16x8*)out)[k] = o;
}

// ---------------------------------------------------------------- gemm C = A * B^T
// 256x256 tile, BK=64, 8 waves 2(M)x4(N). LDS: 32 subfrags of 1KB per operand
// per slot; subfrag (frag,ks): entry l -> row frag*16+(l&15), k ks*32+(l>>4)*8.
// Slots by tile parity. 4 phases per K-tile (af quadrants mq0..3):
//   { stage 1 half-tile ; prefetch next phase's af ds_reads ; 8 MFMA pairs ;
//     [VM(4) @ c2] ; BAR }
// Stage ledger (>=1 barrier between last read and overwrite, verified R5):
//   x.c0: A(x+1)h1   x.c1: B(x+2)h0   x.c2: B(x+2)h1 +VM(4)   x.c3: A(x+2)h0
// bg (next tile's B) reloaded at x.c3 after mma -- landed per VM(4) at x.c2.
template <int EPI>
__global__ __launch_bounds__(512, 2)
void gemm256(const bf16_t* __restrict__ A, const bf16_t* __restrict__ B,
             void* __restrict__ Cv, float* __restrict__ rowsum,
             const int K, const int N, const int nN) {
  __shared__ char lds[131072];

  const int tid = threadIdx.x;
  const int l   = tid & 63;
  const int w   = tid >> 6;       // 0..7
  const int wr  = w >> 2;         // 0..1  (M)
  const int wc  = w & 3;          // 0..3  (N)
  const int lr  = l & 15;
  const int lk  = (l >> 4) << 3;  // 0,8,16,24

  // bijective XCD swizzle (nwg % 8 == 0); n-fast within chunk
  const int nwg   = gridDim.x;
  const int chunk = nwg >> 3;
  const int wg    = (blockIdx.x & 7) * chunk + (blockIdx.x >> 3);
  const int m0    = (wg / nN) * 256;
  const int n0    = (wg % nN) * 256;

  // staging: thread (w,l), j in {0,1} -> subfrag s=j*8+w of a half-tile
  int aoff[2][2], boff[2][2];
#pragma unroll
  for (int h = 0; h < 2; ++h)
#pragma unroll
    for (int j = 0; j < 2; ++j) {
      const int s     = j * 8 + w;
      const int mfrag = h * 8 + (s >> 1);
      const int ks    = s & 1;
      aoff[h][j] = (m0 + mfrag * 16 + lr) * K + ks * 32 + lk;
      boff[h][j] = (n0 + mfrag * 16 + lr) * K + ks * 32 + lk;
    }

  auto stageA = [&](int slot, int kt, int h) {
#pragma unroll
    for (int j = 0; j < 2; ++j) {
      const int s  = j * 8 + w;
      const int sf = (h * 8 + (s >> 1)) * 2 + (s & 1);
      async_copy16(A + aoff[h][j] + kt * 64, lds + slot * 65536 + sf * 1024);
    }
  };
  auto stageB = [&](int slot, int kt, int h) {
#pragma unroll
    for (int j = 0; j < 2; ++j) {
      const int s  = j * 8 + w;
      const int sf = (h * 8 + (s >> 1)) * 2 + (s & 1);
      async_copy16(B + boff[h][j] + kt * 64,
                   lds + slot * 65536 + 32768 + sf * 1024);
    }
  };

  // fragment registers: af double-buffered (2x16 VGPR), bg single (32 VGPR)
  bf16x8 afA[2][2], afB[2][2];
  bf16x8 bg[4][2];

  auto loadAf = [&](bf16x8 (&dst)[2][2], int slot, int mq) {
#pragma unroll
    for (int q = 0; q < 2; ++q)
#pragma unroll
      for (int ks = 0; ks < 2; ++ks)
        dst[q][ks] = *(const bf16x8*)(lds + slot * 65536 +
                        ((4 * mq + 2 * q + wr) * 2 + ks) * 1024 + l * 16);
  };
  auto loadBg = [&](int slot) {
#pragma unroll
    for (int nt = 0; nt < 4; ++nt)
#pragma unroll
      for (int ks = 0; ks < 2; ++ks)
        bg[nt][ks] = *(const bf16x8*)(lds + slot * 65536 + 32768 +
                        ((nt * 4 + wc) * 2 + ks) * 1024 + l * 16);
  };

  const floatx4 z = {0.f, 0.f, 0.f, 0.f};
  floatx4 acc[8][4];
#pragma unroll
  for (int mt = 0; mt < 8; ++mt)
#pragma unroll
    for (int nt = 0; nt < 4; ++nt) acc[mt][nt] = z;

  auto mma = [&](const bf16x8 (&af)[2][2], int mq) {
    __builtin_amdgcn_s_setprio(1);
#pragma unroll
    for (int q = 0; q < 2; ++q)
#pragma unroll
      for (int nt = 0; nt < 4; ++nt)
#pragma unroll
        for (int ks = 0; ks < 2; ++ks)
          acc[2 * mq + q][nt] = __builtin_amdgcn_mfma_f32_16x16x32_bf16(
              af[q][ks], bg[nt][ks], acc[2 * mq + q][nt], 0, 0, 0);
    __builtin_amdgcn_s_setprio(0);
  };

#define BAR()    do { __builtin_amdgcn_s_barrier(); \
                      __builtin_amdgcn_sched_barrier(0); } while (0)
#define VM(n)    asm volatile("s_waitcnt vmcnt(" #n ")" ::: "memory")

  const int T = K >> 6;  // 12 (K=768) or 64 (K=4096); even, >= 4

  // prologue: tile0 full + tile1 {B-h0, B-h1, A-h0}; tile1 A-h1 at 0.c0
  stageA(0, 0, 0); stageA(0, 0, 1); stageB(0, 0, 0); stageB(0, 0, 1);
  stageB(1, 1, 0); stageB(1, 1, 1); stageA(1, 1, 0);
  VM(6);  // tile0's 8 loads landed; tile1's 6 stay in flight
  BAR();
  loadAf(afA, 0, 0);
  loadBg(0);

#pragma unroll 1
  for (int x = 0; x + 3 < T; x += 2) {    // pairs; even tile -> slot0
    // ---- tile x (even, slot0) ----
    stageA(1, x + 1, 1);                  // A(x+1) h1
    loadAf(afB, 0, 1);
    mma(afA, 0); BAR();
    stageB(0, x + 2, 0);                  // B(x+2) h0
    loadAf(afA, 0, 2);
    mma(afB, 1); BAR();
    stageB(0, x + 2, 1);                  // B(x+2) h1
    loadAf(afB, 0, 3);
    mma(afA, 2);
    VM(4);                                // tile x+1 fully landed
    BAR();
    stageA(0, x + 2, 0);                  // A(x+2) h0
    loadAf(afA, 1, 0);
    mma(afB, 3);
    loadBg(1);                            // bg <- B(x+1) (after last use)
    BAR();
    // ---- tile x+1 (odd, slot1) ----
    stageA(0, x + 2, 1);                  // A(x+2) h1
    loadAf(afB, 1, 1);
    mma(afA, 0); BAR();
    stageB(1, x + 3, 0);                  // B(x+3) h0
    loadAf(afA, 1, 2);
    mma(afB, 1); BAR();
    stageB(1, x + 3, 1);                  // B(x+3) h1
    loadAf(afB, 1, 3);
    mma(afA, 2);
    VM(4);                                // tile x+2 fully landed
    BAR();
    stageA(1, x + 3, 0);                  // A(x+3) h0
    loadAf(afA, 0, 0);                    // af(x+2, mq0)
    mma(afB, 3);
    loadBg(0);                            // bg <- B(x+2)
    BAR();
  }

  // ---- tail: tiles T-2 (slot0) and T-1 (slot1) ----
  stageA(1, T - 1, 1);                    // A(T-1) h1 (last stage)
  loadAf(afB, 0, 1);
  mma(afA, 0); BAR();
  loadAf(afA, 0, 2);
  mma(afB, 1); BAR();
  loadAf(afB, 0, 3);
  mma(afA, 2);
  VM(0);                                  // everything landed
  BAR();
  loadAf(afA, 1, 0);
  mma(afB, 3);
  loadBg(1);
  BAR();
  loadAf(afB, 1, 1);
  mma(afA, 0); BAR();
  loadAf(afA, 1, 2);
  mma(afB, 1); BAR();
  loadAf(afB, 1, 3);
  mma(afA, 2); BAR();
  mma(afB, 3);

#undef BAR
#undef VM

  // C/D layout: col = lane&15, row = (lane>>4)*4 + i
  // frag (mt,nt): row = m0+(mt*2+wr)*16+(l>>4)*4+i, col = n0+(nt*4+wc)*16+lr
  const int hi4 = (l >> 4) << 2;
  if (EPI == 0) {
    bf16_t* P = (bf16_t*)Cv;
#pragma unroll
    for (int mt = 0; mt < 8; ++mt) {
      const int row = m0 + (mt * 2 + wr) * 16 + hi4;
      float rs[4] = {0.f, 0.f, 0.f, 0.f};
#pragma unroll
      for (int nt = 0; nt < 4; ++nt) {
        const int col = n0 + (nt * 4 + wc) * 16 + lr;
#pragma unroll
        for (int i = 0; i < 4; ++i) {
          const float e = __expf(acc[mt][nt][i] * BETA_F);
          P[(row + i) * N + col] = (bf16_t)e;
          rs[i] += e;
        }
      }
#pragma unroll
      for (int i = 0; i < 4; ++i) {  // reduce over the 16 col-lanes
        float s = rs[i];
        s += __shfl_xor(s, 1);
        s += __shfl_xor(s, 2);
        s += __shfl_xor(s, 4);
        s += __shfl_xor(s, 8);
        if (lr == 0) atomicAdd(&rowsum[row + i], s);
      }
    }
  } else {
    float* O = (float*)Cv;
#pragma unroll
    for (int mt = 0; mt < 8; ++mt) {
      const int row = m0 + (mt * 2 + wr) * 16 + hi4;
#pragma unroll
      for (int i = 0; i < 4; ++i) {
        const float inv = 1.0f / rowsum[row + i];
#pragma unroll
        for (int nt = 0; nt < 4; ++nt)
          O[(row + i) * N + n0 + (nt * 4 + wc) * 16 + lr] = acc[mt][nt][i] * inv;
      }
    }
  }
}

// ---------------------------------------------------------------- fallback (no ws)
__global__ __launch_bounds__(256) void hopfield_fallback(
    const float* __restrict__ x, const float* __restrict__ wl,
    const float* __restrict__ wc, float* __restrict__ out) {
  __shared__ float  xs[8 * 768];
  __shared__ bf16_t ps[8 * 4096];
  __shared__ float  rs[8];
  const int tid = threadIdx.x;
  const int r0  = blockIdx.x * 8;
  if (tid < 8) rs[tid] = 0.f;
  for (int i = tid; i < 8 * 768; i += 256)
    xs[i] = x[(r0 + (i / 768)) * 768 + (i % 768)];
  __syncthreads();

  float lsum[8] = {0, 0, 0, 0, 0, 0, 0, 0};
  for (int p = tid; p < 4096; p += 256) {
    float s[8] = {0, 0, 0, 0, 0, 0, 0, 0};
    for (int d = 0; d < 768; ++d) {
      const float wv = wl[p * 768 + d];
#pragma unroll
      for (int r = 0; r < 8; ++r) s[r] += xs[r * 768 + d] * wv;
    }
#pragma unroll
    for (int r = 0; r < 8; ++r) {
      const float e = __expf(s[r] * BETA_F);
      ps[r * 4096 + p] = (bf16_t)e;
      lsum[r] += e;
    }
  }
#pragma unroll
  for (int r = 0; r < 8; ++r) atomicAdd(&rs[r], lsum[r]);
  __syncthreads();

  for (int d = tid; d < 768; d += 256) {
    float o[8] = {0, 0, 0, 0, 0, 0, 0, 0};
    for (int p = 0; p < 4096; ++p) {
      const float wv = wc[d * 4096 + p];
#pragma unroll
      for (int r = 0; r < 8; ++r) o[r] += (float)ps[r * 4096 + p] * wv;
    }
#pragma unroll
    for (int r = 0; r < 8; ++r) out[(r0 + r) * 768 + d] = o[r] / rs[r];
  }
}

// ---------------------------------------------------------------- launcher
extern "C" void kernel_launch(void* const* d_in, const int* in_sizes, int n_in,
                              void* d_out, int out_size, void* d_ws, size_t ws_size,
                              hipStream_t stream) {
  (void)in_sizes; (void)n_in; (void)out_size;
  const float* x  = (const float*)d_in[0];
  const float* wl = (const float*)d_in[1];
  const float* wc = (const float*)d_in[2];
  float* out = (float*)d_out;

  const size_t xb_e = (size_t)NTOK * DIM;
  const size_t wl_e = (size_t)NPROT * DIM;
  const size_t wc_e = (size_t)DIM * NPROT;
  const size_t P_e  = (size_t)NTOK * NPROT;
  const size_t need = (xb_e + wl_e + wc_e + P_e) * 2 + (size_t)NTOK * 4;

  if (ws_size >= need) {
    char* ws = (char*)d_ws;
    bf16_t* xb  = (bf16_t*)ws;  ws += xb_e * 2;
    bf16_t* wlb = (bf16_t*)ws;  ws += wl_e * 2;
    bf16_t* wcb = (bf16_t*)ws;  ws += wc_e * 2;
    bf16_t* P   = (bf16_t*)ws;  ws += P_e * 2;
    float* rowsum = (float*)ws;

    hipMemsetAsync(rowsum, 0, NTOK * sizeof(float), stream);
    const int nx8 = (int)(xb_e / 8), nw8 = (int)(wl_e / 8), nc8 = (int)(wc_e / 8);
    cvt_all<<<(nx8 + nw8 + nc8 + 255) / 256, 256, 0, stream>>>(
        x, wl, wc, xb, wlb, wcb, nx8, nw8, nc8);
    // scores+exp+rowsum: M=16384, N=4096, K=768 -> 64x16 = 1024 blocks
    gemm256<0><<<dim3((NTOK / 256) * (NPROT / 256)), 512, 0, stream>>>(
        xb, wlb, (void*)P, rowsum, DIM, NPROT, NPROT / 256);
    // content+normalize: M=16384, N=768, K=4096 -> 64x3 = 192 blocks
    gemm256<1><<<dim3((NTOK / 256) * (DIM / 256)), 512, 0, stream>>>(
        P, wcb, (void*)out, rowsum, NPROT, DIM, DIM / 256);
  } else {
    hopfield_fallback<<<NTOK / 8, 256, 0, stream>>>(x, wl, wc, out);
  }
}